// Round 14
// baseline (4125.951 us; speedup 1.0000x reference)
//
#include <hip/hip_runtime.h>
#include <hip/hip_fp16.h>
#include <stdint.h>

typedef _Float16 half8 __attribute__((ext_vector_type(8)));
typedef float f32x4 __attribute__((ext_vector_type(4)));
typedef unsigned long long ull;

__device__ __forceinline__ uint16_t f2h(float f) {
    __half h = __float2half(f);
    return *reinterpret_cast<uint16_t*>(&h);
}
__device__ __forceinline__ float h2f(uint16_t b) {
    return (float)__builtin_bit_cast(_Float16, b);
}
__device__ __forceinline__ uint32_t pk2(float lo, float hi) {
    return (uint32_t)f2h(lo) | ((uint32_t)f2h(hi) << 16);
}
__device__ __forceinline__ float sigm(float v) {
    return __builtin_amdgcn_rcpf(1.f + __expf(-v));
}
__device__ __forceinline__ float tanhfast(float v) {
    float e = __expf(2.f * v);
    return 1.f - 2.f * __builtin_amdgcn_rcpf(e + 1.f);
}

// xg layout (r10-r13 verified): ull idx = ((grp*1024 + t)*256 + gu)*16 + m
// ull = 4 gates f16: f | i<<16 | o<<32 | g<<48.  268,435,456 B in d_ws.

// ---- phase 1: xg = x@wx + bias (r10-r13 verbatim, verified) ----
__global__ __launch_bounds__(512, 1) void xw_gemm(
    const float* __restrict__ x, const float* __restrict__ wx,
    const float* __restrict__ bias, ull* __restrict__ xg)
{
    const int tid = threadIdx.x;
    const int tc = blockIdx.x >> 4;
    const int grp = (blockIdx.x >> 1) & 7;
    const int slice = blockIdx.x & 1;
    const int lane = tid & 63, wave = tid >> 6;
    const int cw = lane & 15, lhi = lane >> 4;
    const int u = wave * 16 + cw;

    __shared__ __align__(16) uint16_t Wxl[512 * 136];       // 139264 B
    __shared__ __align__(16) uint16_t Xl[2][16][33][8];     // 16896 B

    half8 Wxf[4][8];
    #pragma unroll
    for (int p = 0; p < 2; ++p) {
        for (int idx = tid; idx < 512 * 128; idx += 512) {
            int k_l = idx >> 9, c_l = idx & 511;
            int gg = c_l >> 7, uu = c_l & 127;
            int col = gg * 256 + slice * 128 + uu;
            Wxl[c_l * 136 + k_l] = f2h(wx[(size_t)(p * 128 + k_l) * 1024 + col]);
        }
        __syncthreads();
        #pragma unroll
        for (int g = 0; g < 4; ++g)
            #pragma unroll
            for (int jj = 0; jj < 4; ++jj)
                Wxf[g][p * 4 + jj] = *reinterpret_cast<const half8*>(
                    &Wxl[(g * 128 + u) * 136 + jj * 32 + lhi * 8]);
        __syncthreads();
    }
    float bv[4];
    #pragma unroll
    for (int g = 0; g < 4; ++g) bv[g] = bias[g * 256 + slice * 128 + u];

    const int t0 = tc * 64;
    const int m_s = tid >> 5, q_s = tid & 31;
    const float* xrow = &x[((size_t)(grp * 16 + m_s) * 1024) * 256 + q_s * 8];
    {
        const float4* xs = reinterpret_cast<const float4*>(xrow + (size_t)t0 * 256);
        float4 a = xs[0], b = xs[1];
        uint4 pkv = {pk2(a.x, a.y), pk2(a.z, a.w), pk2(b.x, b.y), pk2(b.z, b.w)};
        *reinterpret_cast<uint4*>(&Xl[0][m_s][q_s][0]) = pkv;
    }
    float4 xa, xb;
    {
        const float4* xs = reinterpret_cast<const float4*>(xrow + (size_t)(t0 + 1) * 256);
        xa = xs[0]; xb = xs[1];
    }
    __syncthreads();

    for (int tt = 0; tt < 64; ++tt) {
        const int t = t0 + tt, buf = tt & 1, bn = buf ^ 1;
        if (tt < 63) {
            uint4 pkv = {pk2(xa.x, xa.y), pk2(xa.z, xa.w), pk2(xb.x, xb.y), pk2(xb.z, xb.w)};
            *reinterpret_cast<uint4*>(&Xl[bn][m_s][q_s][0]) = pkv;
        }
        if (tt < 62) {
            const float4* xs = reinterpret_cast<const float4*>(xrow + (size_t)(t + 2) * 256);
            xa = xs[0]; xb = xs[1];
        }
        f32x4 a0 = {0,0,0,0}, a1 = {0,0,0,0}, a2 = {0,0,0,0}, a3 = {0,0,0,0};
        #pragma unroll
        for (int ks = 0; ks < 8; ++ks) {
            half8 av = *reinterpret_cast<const half8*>(&Xl[buf][cw][ks * 4 + lhi][0]);
            a0 = __builtin_amdgcn_mfma_f32_16x16x32_f16(av, Wxf[0][ks], a0, 0, 0, 0);
            a1 = __builtin_amdgcn_mfma_f32_16x16x32_f16(av, Wxf[1][ks], a1, 0, 0, 0);
            a2 = __builtin_amdgcn_mfma_f32_16x16x32_f16(av, Wxf[2][ks], a2, 0, 0, 0);
            a3 = __builtin_amdgcn_mfma_f32_16x16x32_f16(av, Wxf[3][ks], a3, 0, 0, 0);
        }
        #pragma unroll
        for (int r = 0; r < 4; ++r) {
            ull v = (ull)f2h(a0[r] + bv[0])
                  | ((ull)f2h(a1[r] + bv[1]) << 16)
                  | ((ull)f2h(a2[r] + bv[2]) << 32)
                  | ((ull)f2h(a3[r] + bv[3]) << 48);
            xg[(((size_t)(grp * 1024 + t) * 256) + slice * 128 + u) * 16 + lhi * 4 + r] = v;
        }
        __syncthreads();
    }
}

// ---- phase 2 helpers ----
__device__ __forceinline__ half8 loadw(const float* __restrict__ wh,
                                       int col, int kt, int lhi) {
    half8 f;
    #pragma unroll
    for (int e = 0; e < 8; ++e)
        f[e] = (_Float16)wh[(size_t)(kt * 32 + lhi * 8 + e) * 1024 + col];
    return f;
}

// ---- phase 2: recurrence. grid 8, 512 thr, one block per 16-batch group.
// ALL per-thread state in NAMED variables (rule #20: SROA runs before
// unrolling, so any loop-indexed private array -> scratch. r11-r13's
// Wf[48] lived in scratch: VGPR_Count pinned at 128, ~6400cy/step L2
// reload, immune to every occupancy attribute).
__global__ __launch_bounds__(512, 1) void lstm_rec(
    const float* __restrict__ h0, const float* __restrict__ c0,
    const float* __restrict__ wh, float* __restrict__ out,
    const ull* __restrict__ xg)
{
    const int tid = threadIdx.x;
    const int grp = blockIdx.x;           // 0..7
    const int lane = tid & 63, w = tid >> 6;
    const int cw = lane & 15, lhi = lane >> 4;
    const int swzA = cw & 7;

    __shared__ __align__(16) uint16_t Wlds[8][8][2][64][8];  // 128 KB (kt 6,7)
    __shared__ __align__(16) uint16_t Hs[2][16][32][8];      // 16 KB dbuf, slot^(m&7)

    // ---- prologue: 48 named W frags (kt 0..5) + kt 6,7 to LDS ----
#define WROW(J, G, QQ) \
    const int col##J = (G) * 256 + w * 32 + (QQ) * 16 + cw; \
    half8 W##J##0 = loadw(wh, col##J, 0, lhi); \
    half8 W##J##1 = loadw(wh, col##J, 1, lhi); \
    half8 W##J##2 = loadw(wh, col##J, 2, lhi); \
    half8 W##J##3 = loadw(wh, col##J, 3, lhi); \
    half8 W##J##4 = loadw(wh, col##J, 4, lhi); \
    half8 W##J##5 = loadw(wh, col##J, 5, lhi); \
    *reinterpret_cast<half8*>(&Wlds[w][J][0][lane][0]) = loadw(wh, col##J, 6, lhi); \
    *reinterpret_cast<half8*>(&Wlds[w][J][1][lane][0]) = loadw(wh, col##J, 7, lhi);

    WROW(0, 0, 0) WROW(1, 0, 1) WROW(2, 1, 0) WROW(3, 1, 1)
    WROW(4, 2, 0) WROW(5, 2, 1) WROW(6, 3, 0) WROW(7, 3, 1)
#undef WROW

    // ---- h0 -> Hs[0], c -> named regs, xg(t=0) -> named regs ----
    const int uA = w * 32 + cw, uB = uA + 16;
    float cA0, cA1, cA2, cA3, cB0, cB1, cB2, cB3;
    {
        const size_t b0 = (size_t)(grp * 16 + lhi * 4) * 256;
        cA0 = c0[b0 + uA];          cB0 = c0[b0 + uB];
        cA1 = c0[b0 + 256 + uA];    cB1 = c0[b0 + 256 + uB];
        cA2 = c0[b0 + 512 + uA];    cB2 = c0[b0 + 512 + uB];
        cA3 = c0[b0 + 768 + uA];    cB3 = c0[b0 + 768 + uB];
    }
    #pragma unroll
    for (int q = 0; q < 2; ++q)
        #pragma unroll
        for (int r = 0; r < 4; ++r) {
            int m = lhi * 4 + r, u = w * 32 + q * 16 + cw;
            Hs[0][m][(u >> 3) ^ (m & 7)][u & 7] =
                f2h(h0[(size_t)(grp * 16 + m) * 256 + u]);
        }
    const ull* xgb = xg + (size_t)grp * 1024 * 4096;   // 4096 ull per t
    ull xqA0 = xgb[(size_t)uA * 16 + lhi * 4 + 0];
    ull xqA1 = xgb[(size_t)uA * 16 + lhi * 4 + 1];
    ull xqA2 = xgb[(size_t)uA * 16 + lhi * 4 + 2];
    ull xqA3 = xgb[(size_t)uA * 16 + lhi * 4 + 3];
    ull xqB0 = xgb[(size_t)uB * 16 + lhi * 4 + 0];
    ull xqB1 = xgb[(size_t)uB * 16 + lhi * 4 + 1];
    ull xqB2 = xgb[(size_t)uB * 16 + lhi * 4 + 2];
    ull xqB3 = xgb[(size_t)uB * 16 + lhi * 4 + 3];
    __syncthreads();

#define MF(ACC, A, B) ACC = __builtin_amdgcn_mfma_f32_16x16x32_f16(A, B, ACC, 0, 0, 0)
#define LDA(KT) (*reinterpret_cast<const half8*>(&Hs[par][cw][((KT) * 4 + lhi) ^ swzA][0]))
#define LB(J, KK) (*reinterpret_cast<const half8*>(&Wlds[w][J][KK][lane][0]))
#define MFMA4(A, B0, B1, B2, B3) \
    { half8 Av_ = (A); MF(acc0, Av_, B0); MF(acc1, Av_, B1); \
      MF(acc2, Av_, B2); MF(acc3, Av_, B3); }
#define ACCINIT(X0, X1, X2, X3) \
    acc0 = (f32x4){h2f((uint16_t)(X0)), h2f((uint16_t)(X1)), \
                   h2f((uint16_t)(X2)), h2f((uint16_t)(X3))}; \
    acc1 = (f32x4){h2f((uint16_t)((X0) >> 16)), h2f((uint16_t)((X1) >> 16)), \
                   h2f((uint16_t)((X2) >> 16)), h2f((uint16_t)((X3) >> 16))}; \
    acc2 = (f32x4){h2f((uint16_t)((X0) >> 32)), h2f((uint16_t)((X1) >> 32)), \
                   h2f((uint16_t)((X2) >> 32)), h2f((uint16_t)((X3) >> 32))}; \
    acc3 = (f32x4){h2f((uint16_t)((X0) >> 48)), h2f((uint16_t)((X1) >> 48)), \
                   h2f((uint16_t)((X2) >> 48)), h2f((uint16_t)((X3) >> 48))};
#define GATE(CC, R, Q) { \
    float fg_ = sigm(acc0[R]), ig_ = sigm(acc1[R]), og_ = sigm(acc2[R]); \
    float gv_ = tanhfast(acc3[R]); \
    CC = fmaf(CC, fg_, gv_ * ig_); \
    float hv_ = tanhfast(CC) * og_; \
    int m_ = lhi * 4 + (R), u_ = w * 32 + (Q) * 16 + cw; \
    Hs[pn][m_][(u_ >> 3) ^ (m_ & 7)][u_ & 7] = f2h(hv_); \
    out[((size_t)(grp * 16 + m_) * 1024 + t) * 256 + u_] = hv_; }

    // ---- time loop: ONE barrier per step ----
    for (int t = 0; t < 1024; ++t) {
        const int par = t & 1, pn = par ^ 1;
        f32x4 acc0, acc1, acc2, acc3;

        // ---- q = 0 half (cols uA, gate-tiles j = 0,2,4,6) ----
        ACCINIT(xqA0, xqA1, xqA2, xqA3)
        MFMA4(LDA(0), W00, W20, W40, W60)
        MFMA4(LDA(1), W01, W21, W41, W61)
        MFMA4(LDA(2), W02, W22, W42, W62)
        MFMA4(LDA(3), W03, W23, W43, W63)
        MFMA4(LDA(4), W04, W24, W44, W64)
        MFMA4(LDA(5), W05, W25, W45, W65)
        MFMA4(LDA(6), LB(0, 0), LB(2, 0), LB(4, 0), LB(6, 0))
        MFMA4(LDA(7), LB(0, 1), LB(2, 1), LB(4, 1), LB(6, 1))
        GATE(cA0, 0, 0) GATE(cA1, 1, 0) GATE(cA2, 2, 0) GATE(cA3, 3, 0)

        // ---- q = 1 half (cols uB, gate-tiles j = 1,3,5,7) ----
        ACCINIT(xqB0, xqB1, xqB2, xqB3)
        {   // both halves consumed: prefetch xg(t+1) into the named regs
            int tn = (t + 1 < 1024) ? t + 1 : t;
            const ull* pp = xgb + (size_t)tn * 4096;
            xqA0 = pp[(size_t)uA * 16 + lhi * 4 + 0];
            xqA1 = pp[(size_t)uA * 16 + lhi * 4 + 1];
            xqA2 = pp[(size_t)uA * 16 + lhi * 4 + 2];
            xqA3 = pp[(size_t)uA * 16 + lhi * 4 + 3];
            xqB0 = pp[(size_t)uB * 16 + lhi * 4 + 0];
            xqB1 = pp[(size_t)uB * 16 + lhi * 4 + 1];
            xqB2 = pp[(size_t)uB * 16 + lhi * 4 + 2];
            xqB3 = pp[(size_t)uB * 16 + lhi * 4 + 3];
        }
        MFMA4(LDA(0), W10, W30, W50, W70)
        MFMA4(LDA(1), W11, W31, W51, W71)
        MFMA4(LDA(2), W12, W32, W52, W72)
        MFMA4(LDA(3), W13, W33, W53, W73)
        MFMA4(LDA(4), W14, W34, W54, W74)
        MFMA4(LDA(5), W15, W35, W55, W75)
        MFMA4(LDA(6), LB(1, 0), LB(3, 0), LB(5, 0), LB(7, 0))
        MFMA4(LDA(7), LB(1, 1), LB(3, 1), LB(5, 1), LB(7, 1))
        GATE(cB0, 0, 1) GATE(cB1, 1, 1) GATE(cB2, 2, 1) GATE(cB3, 3, 1)

        __syncthreads();   // h(t+1) staged for all waves; old buffer reusable
    }
#undef MF
#undef LDA
#undef LB
#undef MFMA4
#undef ACCINIT
#undef GATE

    // ---- finals: h_f from Hs[0] (t=1023 wrote pn=0), c_f from regs ----
    const size_t fsz = (size_t)128 * 1024 * 256;
    #pragma unroll
    for (int q = 0; q < 2; ++q)
        #pragma unroll
        for (int r = 0; r < 4; ++r) {
            int m = lhi * 4 + r, u = w * 32 + q * 16 + cw;
            int b = grp * 16 + m;
            float cv = (q == 0) ? (r == 0 ? cA0 : r == 1 ? cA1 : r == 2 ? cA2 : cA3)
                                : (r == 0 ? cB0 : r == 1 ? cB1 : r == 2 ? cB2 : cB3);
            out[fsz + (size_t)b * 256 + u] =
                h2f(Hs[0][m][(u >> 3) ^ (m & 7)][u & 7]);
            out[fsz + (size_t)128 * 256 + (size_t)b * 256 + u] = cv;
        }
}

extern "C" void kernel_launch(void* const* d_in, const int* in_sizes, int n_in,
                              void* d_out, int out_size, void* d_ws, size_t ws_size,
                              hipStream_t stream) {
    const float* x    = (const float*)d_in[0];
    const float* h0   = (const float*)d_in[1];
    const float* c0   = (const float*)d_in[2];
    const float* wx   = (const float*)d_in[3];
    const float* wh   = (const float*)d_in[4];
    const float* bias = (const float*)d_in[5];
    float* out = (float*)d_out;
    ull* xgp = (ull*)d_ws;   // fully overwritten by xw_gemm each call: replay-safe

    xw_gemm<<<256, 512, 0, stream>>>(x, wx, bias, xgp);
    lstm_rec<<<8, 512, 0, stream>>>(h0, c0, wh, out, xgp);
}